// Round 7
// baseline (7454.588 us; speedup 1.0000x reference)
//
#include <hip/hip_runtime.h>
#include <hip/hip_bf16.h>

typedef __hip_bfloat16 bf16;
typedef unsigned long long ull;
#define NT 256

__device__ __forceinline__ float b2f(bf16 v){ return __bfloat162float(v); }
__device__ __forceinline__ bf16 f2b(float v){ return __float2bfloat16(v); }
__device__ __forceinline__ float lrelu(float a){ return a>0.f ? a : 0.2f*a; }
__device__ __forceinline__ float sanf(float v){ return __builtin_isfinite(v) ? v : -12345.f; }
__device__ __forceinline__ float us2f(unsigned short u){ return __uint_as_float(((unsigned)u)<<16); }

// dtype-flexible input load: f32in ? float : bf16
__device__ __forceinline__ float ld(const void* p, size_t i, int f32in){
  return f32in ? ((const float*)p)[i] : b2f(((const bf16*)p)[i]);
}

__device__ __forceinline__ float waveReduceSum(float v){
#pragma unroll
  for(int o=32;o>0;o>>=1) v += __shfl_down(v,o,64);
  return v;
}

// monotone float<->uint key for atomicMax on floats
__device__ __forceinline__ unsigned encf(float f){
  unsigned u=__float_as_uint(f);
  return (u&0x80000000u) ? ~u : (u|0x80000000u);
}
__device__ __forceinline__ float decf(unsigned e){
  unsigned u = (e&0x80000000u) ? (e&0x7fffffffu) : ~e;
  return __uint_as_float(u);
}
#define ENC_NEG_INF 0x00800000u

__device__ __forceinline__ unsigned clampi(int v, int n){
  unsigned u=(unsigned)v; return (u<(unsigned)n)?u:0u;
}

struct alignas(8) bf16x4 { bf16 a,b,c,d; };

// vectorized bf16 h1 row load (16 ch = 4x 8B)
__device__ __forceinline__ void load_h1v(const bf16* h1, unsigned node, float* dst){
  const ull* p=(const ull*)(h1+(size_t)node*16);
#pragma unroll
  for(int q=0;q<4;q++){
    ull v=p[q];
    dst[q*4+0]=us2f((unsigned short)v);        dst[q*4+1]=us2f((unsigned short)(v>>16));
    dst[q*4+2]=us2f((unsigned short)(v>>32));  dst[q*4+3]=us2f((unsigned short)(v>>48));
  }
}
// x row (4 ch) load, dtype-flex
__device__ __forceinline__ void load_x4(const void* x, unsigned n, int f32in, float* o){
  if(f32in){ float4 v=((const float4*)x)[n]; o[0]=v.x;o[1]=v.y;o[2]=v.z;o[3]=v.w; }
  else{
    ull v=((const ull*)x)[n];
    o[0]=us2f((unsigned short)v);       o[1]=us2f((unsigned short)(v>>16));
    o[2]=us2f((unsigned short)(v>>32)); o[3]=us2f((unsigned short)(v>>48));
  }
}

// ---------------- K0: zero stats, detect input dtype -> ((int*)stats)[7]
__global__ __launch_bounds__(64) void k_probe(const unsigned short* __restrict__ xraw,
                                              int nscan, float* __restrict__ stats){
  int t=threadIdx.x;
  int bad=0;
  for(int k=t*8;k<t*8+8;k++){
    if(k<nscan){
      unsigned short u=xraw[k];
      unsigned ex=(u>>7)&0xFF;
      bool plaus = (ex==0u) || (ex>=97u && ex<=157u);
      if(!plaus) bad++;
    }
  }
#pragma unroll
  for(int o=32;o>0;o>>=1) bad += __shfl_down(bad,o,64);
  if(t==0){
    for(int i=0;i<7;i++) stats[i]=0.f;
    ((int*)stats)[7] = (bad>=8) ? 1 : 0;
  }
}

// ---------------- K1: histogram of destinations + edge_attr sums -> stats[0..2]
__global__ __launch_bounds__(NT) void k_prep(const void* __restrict__ ea,
                                             const int* __restrict__ idx,
                                             int* __restrict__ rowc,
                                             float* __restrict__ stats, int E, int N){
  const int f32in=((const int*)stats)[7];
  __shared__ float lds[16];
  float s0=0.f,s1=0.f,s2=0.f;
  for(size_t e=(size_t)blockIdx.x*NT+threadIdx.x; e<(size_t)E; e+=(size_t)gridDim.x*NT){
    s0+=ld(ea,e*3+0,f32in); s1+=ld(ea,e*3+1,f32in); s2+=ld(ea,e*3+2,f32in);
    unsigned d=clampi(idx[(size_t)E+e],N);
    atomicAdd(&rowc[d],1);
  }
  int lane=threadIdx.x&63, wv=threadIdx.x>>6;
  s0=waveReduceSum(s0); s1=waveReduceSum(s1); s2=waveReduceSum(s2);
  if(lane==0){ lds[wv*4+0]=s0; lds[wv*4+1]=s1; lds[wv*4+2]=s2; }
  __syncthreads();
  if(threadIdx.x==0){
    float a0=0,a1=0,a2=0;
    for(int w=0;w<NT/64;w++){ a0+=lds[w*4]; a1+=lds[w*4+1]; a2+=lds[w*4+2]; }
    atomicAdd(&stats[0],a0); atomicAdd(&stats[1],a1); atomicAdd(&stats[2],a2);
  }
}

// ---------------- K2: als/ald per node
__global__ __launch_bounds__(NT) void k_node1(
    const void* __restrict__ x, const void* __restrict__ W1,
    const void* __restrict__ as1, const void* __restrict__ ad1,
    const float* __restrict__ stats,
    float* __restrict__ als, float* __restrict__ ald, int N){
  const int f32in=((const int*)stats)[7];
  __shared__ float sW1[64], sas[16], sad[16];
  if(threadIdx.x<64) sW1[threadIdx.x]=ld(W1,threadIdx.x,f32in);
  if(threadIdx.x<16){ sas[threadIdx.x]=ld(as1,threadIdx.x,f32in); sad[threadIdx.x]=ld(ad1,threadIdx.x,f32in); }
  __syncthreads();
  int i=blockIdx.x*NT+threadIdx.x;
  if(i>=N) return;
  float xv[4]; load_x4(x,(unsigned)i,f32in,xv);
  float a_s=0.f,a_d=0.f;
#pragma unroll
  for(int j=0;j<16;j++){
    float v=xv[0]*sW1[j]+xv[1]*sW1[16+j]+xv[2]*sW1[32+j]+xv[3]*sW1[48+j];
    a_s+=v*sas[j]; a_d+=v*sad[j];
  }
  als[i]=a_s; ald[i]=a_d;
}

// ---------------- scan (3 kernels): rowc hist -> exclusive starts
__global__ __launch_bounds__(NT) void k_scan1(const int* __restrict__ rowc, int* __restrict__ bsum, int N){
  __shared__ int sm[NT];
  int i=blockIdx.x*NT+threadIdx.x;
  sm[threadIdx.x]=(i<N)?rowc[i]:0;
  __syncthreads();
  for(int o=NT/2;o>0;o>>=1){ if(threadIdx.x<o) sm[threadIdx.x]+=sm[threadIdx.x+o]; __syncthreads(); }
  if(threadIdx.x==0) bsum[blockIdx.x]=sm[0];
}
__global__ __launch_bounds__(1024) void k_scan2(int* __restrict__ bsum, int NB){
  __shared__ int sm[1024];
  int i=threadIdx.x;
  int v=(i<NB)?bsum[i]:0;
  sm[i]=v; __syncthreads();
  for(int o=1;o<1024;o<<=1){
    int t=(i>=o)?sm[i-o]:0; __syncthreads();
    sm[i]+=t; __syncthreads();
  }
  if(i<NB) bsum[i]=(i==0)?0:sm[i-1];
}
__global__ __launch_bounds__(NT) void k_scan3(int* __restrict__ rowc, const int* __restrict__ bsum, int N){
  __shared__ int sm[NT];
  int i=blockIdx.x*NT+threadIdx.x;
  int v=(i<N)?rowc[i]:0;
  sm[threadIdx.x]=v; __syncthreads();
  for(int o=1;o<NT;o<<=1){
    int t=(threadIdx.x>=o)?sm[threadIdx.x-o]:0; __syncthreads();
    sm[threadIdx.x]+=t; __syncthreads();
  }
  if(i<N) rowc[i]=bsum[blockIdx.x]+sm[threadIdx.x]-v;   // exclusive start
}

// ---------------- K3: scatter packed {src, alpha_partial} into CSR slots; rowc -> end
__global__ __launch_bounds__(NT) void k_scatter(
    const int* __restrict__ idx, const void* __restrict__ ea,
    const void* __restrict__ We1, const void* __restrict__ ae1,
    const float* __restrict__ als, const float* __restrict__ stats,
    int* __restrict__ rowc, ull* __restrict__ csr, int E, int N){
  const int f32in=((const int*)stats)[7];
  __shared__ float sve[3];
  if(threadIdx.x<3){
    float v=0.f;
    for(int j=0;j<16;j++) v+=ld(We1,threadIdx.x*16+j,f32in)*ld(ae1,j,f32in);
    sve[threadIdx.x]=v;
  }
  __syncthreads();
  int e=blockIdx.x*NT+threadIdx.x;
  if(e>=E) return;
  unsigned s=clampi(idx[e],N), d=clampi(idx[(size_t)E+e],N);
  float ap = als[s] + ld(ea,(size_t)e*3+0,f32in)*sve[0]
                    + ld(ea,(size_t)e*3+1,f32in)*sve[1]
                    + ld(ea,(size_t)e*3+2,f32in)*sve[2];
  int pos=atomicAdd(&rowc[d],1);
  csr[pos] = (ull)s | ((ull)__float_as_uint(ap)<<32);
}

// ---------------- K4: gather-aggregate layer-1 softmax; write h1(bf16), h2, als2, ald2
__global__ __launch_bounds__(NT) void k_gather1(
    const ull* __restrict__ csr, const int* __restrict__ rowe,
    const float* __restrict__ als, const float* __restrict__ ald,
    const void* __restrict__ x, const void* __restrict__ W1, const void* __restrict__ b1,
    const void* __restrict__ W2, const void* __restrict__ as2, const void* __restrict__ ad2,
    const void* __restrict__ We1, const void* __restrict__ ae1,
    const float* __restrict__ stats, float invE,
    bf16* __restrict__ h1, float* __restrict__ h2,
    float* __restrict__ als2, float* __restrict__ ald2, int N){
  const int f32in=((const int*)stats)[7];
  __shared__ float sW1[64], sb1[16], sW2[32], sas2[2], sad2[2], saea[1];
  if(threadIdx.x<64) sW1[threadIdx.x]=ld(W1,threadIdx.x,f32in);
  if(threadIdx.x<16) sb1[threadIdx.x]=ld(b1,threadIdx.x,f32in);
  if(threadIdx.x<32) sW2[threadIdx.x]=ld(W2,threadIdx.x,f32in);
  if(threadIdx.x<2){ sas2[threadIdx.x]=ld(as2,threadIdx.x,f32in); sad2[threadIdx.x]=ld(ad2,threadIdx.x,f32in); }
  if(threadIdx.x==0){
    float a=0.f;
    for(int k=0;k<3;k++){
      float v=0.f;
      for(int j=0;j<16;j++) v+=ld(We1,k*16+j,f32in)*ld(ae1,j,f32in);
      a+=stats[k]*v;
    }
    saea[0]=a*invE;
  }
  __syncthreads();
  int n=blockIdx.x*16+(threadIdx.x>>4);
  int c=threadIdx.x&15;
  if(n>=N) return;
  int end=rowe[n];
  int start=(n==0)?0:rowe[n-1];
  float aldn=ald[n], alsn=als[n];
  float aself=lrelu(alsn+aldn+saea[0]);
  float m=aself;
  for(int k=start+c;k<end;k+=16){
    float ap=__uint_as_float((unsigned)(csr[k]>>32));
    m=fmaxf(m,lrelu(ap+aldn));
  }
#pragma unroll
  for(int o=1;o<16;o<<=1) m=fmaxf(m,__shfl_xor(m,o,64));
  float xv[4]; load_x4(x,(unsigned)n,f32in,xv);
  float hc_self=xv[0]*sW1[c]+xv[1]*sW1[16+c]+xv[2]*sW1[32+c]+xv[3]*sW1[48+c];
  float exs=expf(fminf(aself-m,0.f));
  float den=exs, acc=exs*hc_self;
  for(int k=start;k<end;k++){
    ull v=csr[k];
    unsigned src=(unsigned)(v&0xffffffffu);
    float ap=__uint_as_float((unsigned)(v>>32));
    float ex=expf(fminf(lrelu(ap+aldn)-m,0.f));
    den+=ex;
    float xs[4]; load_x4(x,src,f32in,xs);
    float hc=xs[0]*sW1[c]+xs[1]*sW1[16+c]+xs[2]*sW1[32+c]+xs[3]*sW1[48+c];
    acc+=ex*hc;
  }
  float inv=1.f/(den+1e-16f);
  float h1c=acc*inv+sb1[c];
  h1[(size_t)n*16+c]=f2b(h1c);
  float r0=h1c*sW2[c*2+0], r1=h1c*sW2[c*2+1];
#pragma unroll
  for(int o=1;o<16;o<<=1){ r0+=__shfl_xor(r0,o,64); r1+=__shfl_xor(r1,o,64); }
  if(c==0){
    h2[(size_t)n*2+0]=r0; h2[(size_t)n*2+1]=r1;
    als2[n]=r0*sas2[0]+r1*sas2[1];
    ald2[n]=r0*sad2[0]+r1*sad2[1];
  }
}

// ---------------- K5: seed layer-2 amax
__global__ __launch_bounds__(NT) void k_seed(unsigned* __restrict__ amaxu, int N){
  int i=blockIdx.x*NT+threadIdx.x;
  if(i<N) amaxu[i]=ENC_NEG_INF;
}

// ---------------- transposed edge-MLP weights in LDS (float4-readable)
// layout (floats): w0T 16x36 @0 | b0 @576 | w1T 16x16 @592 | b1 @848 |
//                  w2T 8x16 @864 | b2 @992 | w3T 4x8 @1000 | b3 @1032 | ve2 @1036
__device__ __forceinline__ void mlp_preload_T(float* sw,
    const void* mw0,const void* mb0,const void* mw1,const void* mb1,
    const void* mw2,const void* mb2,const void* mw3,const void* mb3,
    const void* We2,const void* ae2,int f32in){
  for(int t=threadIdx.x;t<576;t+=NT){
    int j=t/36, i=t-j*36;
    sw[t] = (i<35) ? ld(mw0,(size_t)i*16+j,f32in) : 0.f;
  }
  for(int t=threadIdx.x;t<256;t+=NT){
    int j=t>>4, i=t&15;
    sw[592+t]=ld(mw1,(size_t)i*16+j,f32in);
  }
  for(int t=threadIdx.x;t<128;t+=NT){
    int j=t>>4, i=t&15;
    sw[864+t]=ld(mw2,(size_t)i*8+j,f32in);
  }
  if(threadIdx.x<32){
    int j=threadIdx.x>>3, i=threadIdx.x&7;
    sw[1000+threadIdx.x]=ld(mw3,(size_t)i*4+j,f32in);
  }
  if(threadIdx.x<16){ sw[576+threadIdx.x]=ld(mb0,threadIdx.x,f32in); sw[848+threadIdx.x]=ld(mb1,threadIdx.x,f32in); }
  if(threadIdx.x<8) sw[992+threadIdx.x]=ld(mb2,threadIdx.x,f32in);
  if(threadIdx.x<4){
    sw[1032+threadIdx.x]=ld(mb3,threadIdx.x,f32in);
    sw[1036+threadIdx.x]=ld(We2,threadIdx.x*2+0,f32in)*ld(ae2,0,f32in)
                        +ld(We2,threadIdx.x*2+1,f32in)*ld(ae2,1,f32in);
  }
  __syncthreads();
}

// dual-edge MLP eval: each LDS float4 weight read feeds BOTH edges
__device__ __forceinline__ void mlp_eval2(const float* __restrict__ z0, const float* __restrict__ z1,
                                          const float* __restrict__ sw,
                                          float* __restrict__ ev0, float* __restrict__ ev1){
  float t10[16], t11[16];
#pragma unroll
  for(int j=0;j<16;j++){
    float a0=sw[576+j], a1=a0;
    const float* r=sw+j*36;
#pragma unroll
    for(int k=0;k<9;k++){
      float4 w=*(const float4*)(r+k*4);
      a0 += w.x*z0[k*4+0]+w.y*z0[k*4+1]+w.z*z0[k*4+2]+w.w*z0[k*4+3];
      a1 += w.x*z1[k*4+0]+w.y*z1[k*4+1]+w.z*z1[k*4+2]+w.w*z1[k*4+3];
    }
    t10[j]=fmaxf(a0,0.f); t11[j]=fmaxf(a1,0.f);
  }
  float t20[16], t21[16];
#pragma unroll
  for(int j=0;j<16;j++){
    float a0=sw[848+j], a1=a0;
    const float* r=sw+592+j*16;
#pragma unroll
    for(int k=0;k<4;k++){
      float4 w=*(const float4*)(r+k*4);
      a0 += w.x*t10[k*4+0]+w.y*t10[k*4+1]+w.z*t10[k*4+2]+w.w*t10[k*4+3];
      a1 += w.x*t11[k*4+0]+w.y*t11[k*4+1]+w.z*t11[k*4+2]+w.w*t11[k*4+3];
    }
    t20[j]=fmaxf(a0,0.f); t21[j]=fmaxf(a1,0.f);
  }
  float t30[8], t31[8];
#pragma unroll
  for(int j=0;j<8;j++){
    float a0=sw[992+j], a1=a0;
    const float* r=sw+864+j*16;
#pragma unroll
    for(int k=0;k<4;k++){
      float4 w=*(const float4*)(r+k*4);
      a0 += w.x*t20[k*4+0]+w.y*t20[k*4+1]+w.z*t20[k*4+2]+w.w*t20[k*4+3];
      a1 += w.x*t21[k*4+0]+w.y*t21[k*4+1]+w.z*t21[k*4+2]+w.w*t21[k*4+3];
    }
    t30[j]=fmaxf(a0,0.f); t31[j]=fmaxf(a1,0.f);
  }
#pragma unroll
  for(int j=0;j<4;j++){
    float a0=sw[1032+j], a1=a0;
    const float* r=sw+1000+j*8;
#pragma unroll
    for(int k=0;k<2;k++){
      float4 w=*(const float4*)(r+k*4);
      a0 += w.x*t30[k*4+0]+w.y*t30[k*4+1]+w.z*t30[k*4+2]+w.w*t30[k*4+3];
      a1 += w.x*t31[k*4+0]+w.y*t31[k*4+1]+w.z*t31[k*4+2]+w.w*t31[k*4+3];
    }
    ev0[j]=a0; ev1[j]=a1;
  }
}

__device__ __forceinline__ void gather_z(const bf16* h1, const void* ea, int f32in,
                                         unsigned s, unsigned d, size_t e, float* z){
  load_h1v(h1,s,z);
  z[16]=ld(ea,e*3+0,f32in); z[17]=ld(ea,e*3+1,f32in); z[18]=ld(ea,e*3+2,f32in);
  load_h1v(h1,d,z+19);
  z[35]=0.f;
}

// ---------------- K6: dual-edge MLP + out1 log_softmax + alpha2 enc-max + mean(e)
__global__ __launch_bounds__(NT) void k_edge2(
    const int* __restrict__ idx, const void* __restrict__ ea,
    const bf16* __restrict__ h1,
    const float* __restrict__ als2, const float* __restrict__ ald2,
    const void* mw0,const void* mb0,const void* mw1,const void* mb1,
    const void* mw2,const void* mb2,const void* mw3,const void* mb3,
    const void* We2,const void* ae2,
    unsigned* __restrict__ amaxu,
    float* __restrict__ stats, void* __restrict__ d_out, int E, int N){
  const int f32in=((const int*)stats)[7];
  __shared__ __align__(16) float sw[1040];
  __shared__ float s_red[16];
  mlp_preload_T(sw,mw0,mb0,mw1,mb1,mw2,mb2,mw3,mb3,We2,ae2,f32in);
  int e0=blockIdx.x*(NT*2)+threadIdx.x;
  int e1=e0+NT;
  bool v0=e0<E, v1=e1<E;
  unsigned s0=0,d0=0,s1=0,d1=0;
  float z0[36], z1[36];
  if(v0){ s0=clampi(idx[e0],N); d0=clampi(idx[(size_t)E+e0],N); gather_z(h1,ea,f32in,s0,d0,(size_t)e0,z0); }
  else { 
#pragma unroll
    for(int i=0;i<36;i++) z0[i]=0.f; }
  if(v1){ s1=clampi(idx[e1],N); d1=clampi(idx[(size_t)E+e1],N); gather_z(h1,ea,f32in,s1,d1,(size_t)e1,z1); }
  else {
#pragma unroll
    for(int i=0;i<36;i++) z1[i]=0.f; }
  float ev0[4], ev1[4];
  mlp_eval2(z0,z1,sw,ev0,ev1);
  float a0s=0.f,a1s=0.f,a2s=0.f,a3s=0.f;
  const float* s_ve2=sw+1036;
  if(v0){
    a0s+=ev0[0]; a1s+=ev0[1]; a2s+=ev0[2]; a3s+=ev0[3];
    float m=fmaxf(fmaxf(ev0[0],ev0[1]),fmaxf(ev0[2],ev0[3]));
    float lse=m+logf(expf(ev0[0]-m)+expf(ev0[1]-m)+expf(ev0[2]-m)+expf(ev0[3]-m));
    if(f32in){
      float4 o; o.x=sanf(ev0[0]-lse); o.y=sanf(ev0[1]-lse); o.z=sanf(ev0[2]-lse); o.w=sanf(ev0[3]-lse);
      ((float4*)((float*)d_out+(size_t)2*N))[e0]=o;
    }else{
      bf16x4 o; o.a=f2b(sanf(ev0[0]-lse)); o.b=f2b(sanf(ev0[1]-lse)); o.c=f2b(sanf(ev0[2]-lse)); o.d=f2b(sanf(ev0[3]-lse));
      ((bf16x4*)((bf16*)d_out+(size_t)2*N))[e0]=o;
    }
    float adot=ev0[0]*s_ve2[0]+ev0[1]*s_ve2[1]+ev0[2]*s_ve2[2]+ev0[3]*s_ve2[3];
    float a2=sanf(lrelu(als2[s0]+ald2[d0]+adot));
    atomicMax(&amaxu[d0],encf(a2));
  }
  if(v1){
    a0s+=ev1[0]; a1s+=ev1[1]; a2s+=ev1[2]; a3s+=ev1[3];
    float m=fmaxf(fmaxf(ev1[0],ev1[1]),fmaxf(ev1[2],ev1[3]));
    float lse=m+logf(expf(ev1[0]-m)+expf(ev1[1]-m)+expf(ev1[2]-m)+expf(ev1[3]-m));
    if(f32in){
      float4 o; o.x=sanf(ev1[0]-lse); o.y=sanf(ev1[1]-lse); o.z=sanf(ev1[2]-lse); o.w=sanf(ev1[3]-lse);
      ((float4*)((float*)d_out+(size_t)2*N))[e1]=o;
    }else{
      bf16x4 o; o.a=f2b(sanf(ev1[0]-lse)); o.b=f2b(sanf(ev1[1]-lse)); o.c=f2b(sanf(ev1[2]-lse)); o.d=f2b(sanf(ev1[3]-lse));
      ((bf16x4*)((bf16*)d_out+(size_t)2*N))[e1]=o;
    }
    float adot=ev1[0]*s_ve2[0]+ev1[1]*s_ve2[1]+ev1[2]*s_ve2[2]+ev1[3]*s_ve2[3];
    float a2=sanf(lrelu(als2[s1]+ald2[d1]+adot));
    atomicMax(&amaxu[d1],encf(a2));
  }
  int lane=threadIdx.x&63, wv=threadIdx.x>>6;
  a0s=waveReduceSum(a0s); a1s=waveReduceSum(a1s); a2s=waveReduceSum(a2s); a3s=waveReduceSum(a3s);
  __syncthreads();
  if(lane==0){ s_red[wv*4]=a0s; s_red[wv*4+1]=a1s; s_red[wv*4+2]=a2s; s_red[wv*4+3]=a3s; }
  __syncthreads();
  if(threadIdx.x==0){
    float b0=0,b1=0,b2=0,b3=0;
    for(int w=0;w<NT/64;w++){ b0+=s_red[w*4]; b1+=s_red[w*4+1]; b2+=s_red[w*4+2]; b3+=s_red[w*4+3]; }
    atomicAdd(&stats[3],b0); atomicAdd(&stats[4],b1); atomicAdd(&stats[5],b2); atomicAdd(&stats[6],b3);
  }
}

// ---------------- K7: fold self-loop alpha into amax, init den2/acc2
__global__ __launch_bounds__(NT) void k_node2b(
    const float* __restrict__ stats, float invE,
    const float* __restrict__ als2, const float* __restrict__ ald2,
    const void* __restrict__ We2, const void* __restrict__ ae2,
    const float* __restrict__ h2,
    unsigned* amaxu, float* __restrict__ denom2, float* __restrict__ acc2, int N){
  const int f32in=((const int*)stats)[7];
  __shared__ float s_ve2[4];
  if(threadIdx.x<4)
    s_ve2[threadIdx.x]=ld(We2,threadIdx.x*2+0,f32in)*ld(ae2,0,f32in)
                      +ld(We2,threadIdx.x*2+1,f32in)*ld(ae2,1,f32in);
  __syncthreads();
  int i=blockIdx.x*NT+threadIdx.x;
  if(i>=N) return;
  float adot=(stats[3]*s_ve2[0]+stats[4]*s_ve2[1]+stats[5]*s_ve2[2]+stats[6]*s_ve2[3])*invE;
  float self=lrelu(als2[i]+ald2[i]+adot);
  float am=fmaxf(decf(amaxu[i]),self);
  ((float*)amaxu)[i]=am;
  float ex=expf(fminf(self-am,0.f));
  denom2[i]=ex;
  acc2[(size_t)i*2+0]=ex*h2[(size_t)i*2+0];
  acc2[(size_t)i*2+1]=ex*h2[(size_t)i*2+1];
}

// ---------------- K8: dual-edge layer-2 pass B: recompute MLP + alpha2, exp scatter
__global__ __launch_bounds__(NT) void k_edge2b(
    const int* __restrict__ idx, const void* __restrict__ ea,
    const bf16* __restrict__ h1,
    const float* __restrict__ als2, const float* __restrict__ ald2,
    const void* mw0,const void* mb0,const void* mw1,const void* mb1,
    const void* mw2,const void* mb2,const void* mw3,const void* mb3,
    const void* We2,const void* ae2,
    const float* __restrict__ stats,
    const float* __restrict__ amaxf, const float* __restrict__ h2,
    float* __restrict__ denom2, float* __restrict__ acc2, int E, int N){
  const int f32in=((const int*)stats)[7];
  __shared__ __align__(16) float sw[1040];
  mlp_preload_T(sw,mw0,mb0,mw1,mb1,mw2,mb2,mw3,mb3,We2,ae2,f32in);
  int e0=blockIdx.x*(NT*2)+threadIdx.x;
  int e1=e0+NT;
  bool v0=e0<E, v1=e1<E;
  unsigned s0=0,d0=0,s1=0,d1=0;
  float z0[36], z1[36];
  if(v0){ s0=clampi(idx[e0],N); d0=clampi(idx[(size_t)E+e0],N); gather_z(h1,ea,f32in,s0,d0,(size_t)e0,z0); }
  else {
#pragma unroll
    for(int i=0;i<36;i++) z0[i]=0.f; }
  if(v1){ s1=clampi(idx[e1],N); d1=clampi(idx[(size_t)E+e1],N); gather_z(h1,ea,f32in,s1,d1,(size_t)e1,z1); }
  else {
#pragma unroll
    for(int i=0;i<36;i++) z1[i]=0.f; }
  float ev0[4], ev1[4];
  mlp_eval2(z0,z1,sw,ev0,ev1);
  const float* s_ve2=sw+1036;
  if(v0){
    float adot=ev0[0]*s_ve2[0]+ev0[1]*s_ve2[1]+ev0[2]*s_ve2[2]+ev0[3]*s_ve2[3];
    float a2=sanf(lrelu(als2[s0]+ald2[d0]+adot));
    float ex=expf(fminf(a2-amaxf[d0],0.f));
    atomicAdd(&denom2[d0],ex);
    atomicAdd(&acc2[(size_t)d0*2+0],ex*h2[(size_t)s0*2+0]);
    atomicAdd(&acc2[(size_t)d0*2+1],ex*h2[(size_t)s0*2+1]);
  }
  if(v1){
    float adot=ev1[0]*s_ve2[0]+ev1[1]*s_ve2[1]+ev1[2]*s_ve2[2]+ev1[3]*s_ve2[3];
    float a2=sanf(lrelu(als2[s1]+ald2[d1]+adot));
    float ex=expf(fminf(a2-amaxf[d1],0.f));
    atomicAdd(&denom2[d1],ex);
    atomicAdd(&acc2[(size_t)d1*2+0],ex*h2[(size_t)s1*2+0]);
    atomicAdd(&acc2[(size_t)d1*2+1],ex*h2[(size_t)s1*2+1]);
  }
}

// ---------------- K9: layer-2 epilogue + out0 log_softmax
__global__ __launch_bounds__(NT) void k_node3(
    const float* __restrict__ denom2, const float* __restrict__ acc2,
    const void* __restrict__ bias2, const float* __restrict__ stats,
    void* __restrict__ d_out, int N){
  const int f32in=((const int*)stats)[7];
  __shared__ float s_b2[2];
  if(threadIdx.x<2) s_b2[threadIdx.x]=ld(bias2,threadIdx.x,f32in);
  __syncthreads();
  int i=blockIdx.x*NT+threadIdx.x;
  if(i>=N) return;
  float inv=1.f/(denom2[i]+1e-16f);
  float o0=acc2[(size_t)i*2+0]*inv+s_b2[0];
  float o1=acc2[(size_t)i*2+1]*inv+s_b2[1];
  float m=fmaxf(o0,o1);
  float lse=m+logf(expf(o0-m)+expf(o1-m));
  float r0=sanf(o0-lse), r1=sanf(o1-lse);
  if(f32in){
    float* o=(float*)d_out;
    o[(size_t)i*2+0]=r0; o[(size_t)i*2+1]=r1;
  }else{
    bf16* o=(bf16*)d_out;
    o[(size_t)i*2+0]=f2b(r0); o[(size_t)i*2+1]=f2b(r1);
  }
}

extern "C" void kernel_launch(void* const* d_in, const int* in_sizes, int n_in,
                              void* d_out, int out_size, void* d_ws, size_t ws_size,
                              hipStream_t stream){
  const void* x   =d_in[0];
  const void* ea  =d_in[1];
  const void* W1  =d_in[2];
  const void* as1 =d_in[3];
  const void* ad1 =d_in[4];
  const void* We1 =d_in[5];
  const void* ae1 =d_in[6];
  const void* b1  =d_in[7];
  const void* mw0 =d_in[8];
  const void* mb0 =d_in[9];
  const void* mw1 =d_in[10];
  const void* mb1 =d_in[11];
  const void* mw2 =d_in[12];
  const void* mb2 =d_in[13];
  const void* mw3 =d_in[14];
  const void* mb3 =d_in[15];
  const void* W2  =d_in[16];
  const void* as2 =d_in[17];
  const void* ad2 =d_in[18];
  const void* We2 =d_in[19];
  const void* ae2 =d_in[20];
  const void* bias2=d_in[21];
  const int*  idx =(const int*)d_in[22];

  int N=in_sizes[0]/4;
  int E=in_sizes[1]/3;
  float invE=1.f/(float)E;

  // ---- ws layout (floats), total (16N+8)*4 = 6.40 MB @ N=100k (R5/R6-proven)
  float*    F     =(float*)d_ws;
  float*    stats =F;                         // 8
  float*    als   =F+8;                       // N   (als2 aliases after gather1)
  float*    ald   =als+N;                     // N   (den2 aliases after gather1)
  float*    ald2  =ald+N;                     // N
  int*      rowc  =(int*)(ald2+N);            // N   (hist -> start -> end -> amax2)
  unsigned* amaxu =(unsigned*)rowc;
  float*    amaxf =(float*)rowc;
  bf16*     h1    =(bf16*)(rowc+N);           // 16N bf16 = 8N floats
  float*    h2    =(float*)(h1+(size_t)16*N); // 2N
  float*    acc2  =h2+(size_t)2*N;            // 2N
  float*    den2  =ald;

  // ---- CSR (packed {src, alpha_partial}, 8B x E) in d_out at byte offset 4N:
  //      dead before k_edge2 writes out1 and before k_node3 writes out0.
  ull* csr =(ull*)((char*)d_out+(size_t)4*N);
  int* bsum=(int*)((char*)d_out+(size_t)4*N);   // scan scratch, dead before scatter

  int NBn=(N+NT-1)/NT, nbE=(E+NT-1)/NT, nbE2=(E+2*NT-1)/(2*NT);
  int nscan=in_sizes[0]*2; if(nscan>512) nscan=512;

  hipMemsetAsync(rowc,0,(size_t)N*sizeof(int),stream);
  k_probe  <<<1,64,0,stream>>>((const unsigned short*)x,nscan,stats);
  k_prep   <<<1024,NT,0,stream>>>(ea,idx,rowc,stats,E,N);
  k_node1  <<<NBn,NT,0,stream>>>(x,W1,as1,ad1,stats,als,ald,N);
  k_scan1  <<<NBn,NT,0,stream>>>(rowc,bsum,N);
  k_scan2  <<<1,1024,0,stream>>>(bsum,NBn);
  k_scan3  <<<NBn,NT,0,stream>>>(rowc,bsum,N);
  k_scatter<<<nbE,NT,0,stream>>>(idx,ea,We1,ae1,als,stats,rowc,csr,E,N);
  k_gather1<<<(N+15)/16,NT,0,stream>>>(csr,rowc,als,ald,x,W1,b1,W2,as2,ad2,We1,ae1,
                                       stats,invE,h1,h2,als,ald2,N);
  k_seed   <<<NBn,NT,0,stream>>>(amaxu,N);
  k_edge2  <<<nbE2,NT,0,stream>>>(idx,ea,h1,als,ald2,mw0,mb0,mw1,mb1,mw2,mb2,mw3,mb3,
                                  We2,ae2,amaxu,stats,d_out,E,N);
  k_node2b <<<NBn,NT,0,stream>>>(stats,invE,als,ald2,We2,ae2,h2,amaxu,den2,acc2,N);
  k_edge2b <<<nbE2,NT,0,stream>>>(idx,ea,h1,als,ald2,mw0,mb0,mw1,mb1,mw2,mb2,mw3,mb3,
                                  We2,ae2,stats,amaxf,h2,den2,acc2,E,N);
  k_node3  <<<NBn,NT,0,stream>>>(den2,acc2,bias2,stats,d_out,N);
}